// Round 7
// baseline (218.077 us; speedup 1.0000x reference)
//
#include <hip/hip_runtime.h>
#include <stdint.h>

// Mimic numpy (no FMA contraction) for all math feeding discrete decisions.
#pragma clang fp contract(off)

#define BS 32
#define NANCH 90000
#define KEEP_PRE 1000
#define KEEP_POST 300
#define NMS_THR 0.7f
#define NBINS 4096      // top-12-bit histogram of monotone float bits
#define CAND_MAX 4096
#define MW 16           // u64 mask words per NMS row (16*64 = 1024 >= 1000)
#define CNT_STRIDE 32   // u32s between per-image counters (128 B = 1 cacheline)

typedef unsigned long long u64;
typedef unsigned int u32;

// ---- workspace layout (bytes) ----
#define HIST_BYTES ((size_t)BS * NBINS * 4)          // 524288, zeroed each call
#define CNT_OFF    (HIST_BYTES)                      // u32[BS*CNT_STRIDE], zeroed
#define CNT_BYTES  ((size_t)BS * CNT_STRIDE * 4)     // 4096
#define BTHR_OFF   (CNT_OFF + CNT_BYTES)             // u32[BS]
#define CAND_OFF   (BTHR_OFF + 128)                  // u64[BS][CAND_MAX]
#define BOX_OFF    (CAND_OFF + (size_t)BS * CAND_MAX * 8)   // float4[BS][KEEP_PRE]
#define SCORE_OFF  (BOX_OFF + (size_t)BS * KEEP_PRE * 16)   // float[BS][KEEP_PRE]
#define MASK_OFF   (SCORE_OFF + (size_t)BS * KEEP_PRE * 4)  // u64[BS][KEEP_PRE][MW]
// total ~6.03 MB

__device__ __forceinline__ u32 fmono(float f) {
    u32 u = __float_as_uint(f);
    return (u & 0x80000000u) ? ~u : (u | 0x80000000u);  // order-preserving bits
}

// ---- Kernel A: per-image 4096-bin histogram of top-12 monotone bits ----
__global__ __launch_bounds__(256) void hist_kernel(const float* __restrict__ logits,
                                                   u32* __restrict__ hist) {
    __shared__ u32 lh[NBINS];
    const int b = blockIdx.y;
    for (int i = threadIdx.x; i < NBINS; i += 256) lh[i] = 0;
    __syncthreads();
    const float* src = logits + (size_t)b * NANCH;
    const int stride = 256 * gridDim.x;
    for (int i = blockIdx.x * 256 + threadIdx.x; i < NANCH; i += stride) {
        u32 m = fmono(src[i]);
        atomicAdd(&lh[m >> 20], 1u);
    }
    __syncthreads();
    u32* gh = hist + (size_t)b * NBINS;
    for (int i = threadIdx.x; i < NBINS; i += 256)
        if (lh[i]) atomicAdd(&gh[i], lh[i]);
}

// ---- Kernel B: find threshold bin B s.t. count(bin >= B) >= KEEP_PRE ----
__global__ __launch_bounds__(256) void thresh_kernel(const u32* __restrict__ hist,
                                                     u32* __restrict__ Bthr) {
    __shared__ u32 part[256];
    const int b = blockIdx.x;
    const u32* h = hist + (size_t)b * NBINS;
    u32 s = 0;
    for (int k = 0; k < 16; k++) s += h[threadIdx.x * 16 + k];
    part[threadIdx.x] = s;
    __syncthreads();
    if (threadIdx.x == 0) {
        u32 cum = 0;
        int c = 255;
        for (; c >= 0; c--) {
            if (cum + part[c] >= KEEP_PRE) break;
            cum += part[c];
        }
        if (c < 0) c = 0;
        int bin = c * 16 + 15;
        for (; bin >= c * 16; bin--) {
            if (cum + h[bin] >= KEEP_PRE) break;
            cum += h[bin];
        }
        if (bin < c * 16) bin = c * 16;
        Bthr[b] = (u32)bin;
    }
}

// ---- Kernel C: compact candidates (key = monotone<<32 | ~idx) ----
__global__ __launch_bounds__(256) void compact_kernel(const float* __restrict__ logits,
                                                      const u32* __restrict__ Bthr,
                                                      u32* __restrict__ cnt,
                                                      u64* __restrict__ cand) {
    const int b = blockIdx.y;
    const int i = blockIdx.x * 256 + threadIdx.x;
    __shared__ u32 blk_cnt;
    __shared__ u32 blk_base;
    if (threadIdx.x == 0) blk_cnt = 0;
    __syncthreads();
    bool is_cand = false;
    u32 m = 0;
    if (i < NANCH) {
        m = fmono(logits[(size_t)b * NANCH + i]);
        is_cand = (m >> 20) >= Bthr[b];
    }
    u64 ballot = __ballot(is_cand);
    const u32 lane = threadIdx.x & 63;
    u32 wbase = 0;
    u32 old = 0;
    if (ballot) {
        if (lane == 0) old = atomicAdd(&blk_cnt, (u32)__popcll(ballot));
        wbase = __shfl(old, 0);
    }
    __syncthreads();
    if (threadIdx.x == 0 && blk_cnt)
        blk_base = atomicAdd(&cnt[b * CNT_STRIDE], blk_cnt);
    __syncthreads();
    if (is_cand) {
        u32 prefix = (u32)__popcll(ballot & ((1ull << lane) - 1ull));
        u32 pos = blk_base + wbase + prefix;
        if (pos < CAND_MAX)
            cand[(size_t)b * CAND_MAX + pos] = ((u64)m << 32) | (u32)(~(u32)i);
    }
}

// ---- Kernel D: rank-select top 1000 (replaces bitonic sort) ----
// Key's output position = #(strictly greater keys). Keys unique (index bits
// differ), so ranks are a permutation. Inner loop reads keys[j] at a uniform
// address -> LDS hardware broadcast, conflict-free, no barriers.
__global__ __launch_bounds__(1024) void select_kernel(const float* __restrict__ deltas,
                                                      const float* __restrict__ anchors,
                                                      const u32* __restrict__ cnt,
                                                      const u64* __restrict__ cand,
                                                      float4* __restrict__ selbox,
                                                      float* __restrict__ selscore,
                                                      const int* __restrict__ p_img_h,
                                                      const int* __restrict__ p_img_w) {
    __shared__ u64 keys[CAND_MAX];
    const int b = blockIdx.x;
    const int n = (int)min(cnt[b * CNT_STRIDE], (u32)CAND_MAX);
    const u64* src = cand + (size_t)b * CAND_MAX;
    for (int i = threadIdx.x; i < n; i += 1024)
        keys[i] = src[i];
    __syncthreads();
    const float W = (float)(*p_img_w);
    const float H = (float)(*p_img_h);
    const float4* d4 = (const float4*)deltas;
    const float4* a4 = (const float4*)anchors;
    for (int base = 0; base < n; base += 1024) {
        const int i = base + threadIdx.x;
        if (i >= n) break;
        const u64 me = keys[i];
        int rank = 0;
        int j = 0;
        for (; j + 4 <= n; j += 4) {
            rank += (keys[j] > me) + (keys[j + 1] > me)
                  + (keys[j + 2] > me) + (keys[j + 3] > me);
        }
        for (; j < n; j++) rank += (keys[j] > me);
        if (rank < KEEP_PRE) {
            u32 idx = ~(u32)me;
            u32 m = (u32)(me >> 32);
            u32 ub = (m & 0x80000000u) ? (m ^ 0x80000000u) : ~m;
            float logit = __uint_as_float(ub);
            float score = 1.0f / (1.0f + expf(-logit));
            float4 d = d4[(size_t)b * NANCH + idx];
            float4 a = a4[idx];
            float aw = a.z - a.x, ah = a.w - a.y;
            float acx = a.x + 0.5f * aw, acy = a.y + 0.5f * ah;
            float cx = d.x * aw + acx, cy = d.y * ah + acy;
            float w = expf(d.z) * aw, h = expf(d.w) * ah;
            float x1 = cx - 0.5f * w, y1 = cy - 0.5f * h;
            float x2 = cx + 0.5f * w, y2 = cy + 0.5f * h;
            x1 = fminf(fmaxf(x1, 0.0f), W); y1 = fminf(fmaxf(y1, 0.0f), H);
            x2 = fminf(fmaxf(x2, 0.0f), W); y2 = fminf(fmaxf(y2, 0.0f), H);
            selbox[(size_t)b * KEEP_PRE + rank] = make_float4(x1, y1, x2, y2);
            selscore[(size_t)b * KEEP_PRE + rank] = score;
        }
    }
}

// ---- Kernel E: IoU>thr suppression bitmask, mask[b][i][w] covers cols 64w..64w+63 ----
__global__ __launch_bounds__(256) void iou_kernel(const float4* __restrict__ selbox,
                                                  u64* __restrict__ mask) {
    const int b = blockIdx.y;
    const int w = blockIdx.x & 15;
    const int chunk = blockIdx.x >> 4;
    const int i = chunk * 256 + threadIdx.x;
    __shared__ float4 cb[64];
    __shared__ float ca[64];
    if (threadIdx.x < 64) {
        int j = w * 64 + threadIdx.x;
        float4 bx = (j < KEEP_PRE) ? selbox[(size_t)b * KEEP_PRE + j]
                                   : make_float4(0, 0, 0, 0);
        cb[threadIdx.x] = bx;
        ca[threadIdx.x] = (bx.z - bx.x) * (bx.w - bx.y);
    }
    __syncthreads();
    if (i >= KEEP_PRE) return;
    float4 bi = selbox[(size_t)b * KEEP_PRE + i];
    float ai = (bi.z - bi.x) * (bi.w - bi.y);
    u64 bits = 0;
    const int jbase = w * 64;
    for (int jj = 0; jj < 64; jj++) {
        int j = jbase + jj;
        if (j > i && j < KEEP_PRE) {
            float4 bj = cb[jj];
            float ltx = fmaxf(bi.x, bj.x), lty = fmaxf(bi.y, bj.y);
            float rbx = fminf(bi.z, bj.z), rby = fminf(bi.w, bj.w);
            float wx = fmaxf(rbx - ltx, 0.0f), wy = fmaxf(rby - lty, 0.0f);
            float inter = wx * wy;
            float denom = ai + ca[jj] - inter + 1e-12f;
            if (inter / denom > NMS_THR) bits |= (1ull << jj);
        }
    }
    mask[((size_t)b * KEEP_PRE + i) * MW + w] = bits;
}

// ---- Kernel F: sequential greedy NMS, word-aligned branchless scan ----
#define CH_ROWS 64
#define CH_WORDS (CH_ROWS * MW)          // 1024 u64 = 8 KB
#define NCHUNK ((KEEP_PRE + CH_ROWS - 1) / CH_ROWS)   // 16 (last chunk 40 rows)

__global__ __launch_bounds__(256) void nms_out_kernel(const u64* __restrict__ mask,
                                                      const float4* __restrict__ selbox,
                                                      const float* __restrict__ selscore,
                                                      float* __restrict__ out) {
    const int b = blockIdx.x;
    __shared__ u64 lbuf[2][CH_WORDS];
    __shared__ u64 keepw[MW];
    __shared__ u32 wpre[MW + 1];
    __shared__ int ls_stop;
    const int tid = threadIdx.x;
    const u64* mrow = mask + (size_t)b * KEEP_PRE * MW;

    auto load_chunk = [&](int c) {
        int idx = tid - 128;
        if (idx < 0) return;
        const int words = (c == NCHUNK - 1)
                            ? (KEEP_PRE - (NCHUNK - 1) * CH_ROWS) * MW   // 640
                            : CH_WORDS;                                  // 1024
        const u64* gsrc = mrow + (size_t)c * CH_WORDS;
        u64* dst = lbuf[c & 1];
#pragma unroll
        for (int k = 0; k < 4; k++) {
            int off = k * 256 + idx * 2;
            ulonglong2 v;
            if (off < words) v = *(const ulonglong2*)(gsrc + off);
            else { v.x = 0ull; v.y = 0ull; }
            *(ulonglong2*)(dst + off) = v;
        }
    };

    if (tid == 0) ls_stop = 0;
    load_chunk(0);
    __syncthreads();

    u64 remv = 0;
    int kept_total = 0;
    const int lw = tid & 15;
    for (int c = 0; c < NCHUNK; c++) {
        if (c + 1 < NCHUNK) load_chunk(c + 1);
        if (tid < 64) {
            const u64* lb = lbuf[c & 1];
            u64 cur = __shfl(remv, c);   // word c of accumulated suppression
#pragma unroll
            for (int blk = 0; blk < 8; blk++) {
                u64 R[8], rwv[8];
#pragma unroll
                for (int k = 0; k < 8; k++)
                    R[k] = lb[(size_t)(blk * 8 + k) * MW + lw];       // lane word
#pragma unroll
                for (int k = 0; k < 8; k++)
                    rwv[k] = lb[(size_t)(blk * 8 + k) * MW + c];      // broadcast word c
#pragma unroll
                for (int k = 0; k < 8; k++) {
                    const int p = blk * 8 + k;                        // compile-time
                    u64 msk = ((cur >> p) & 1ull) ? 0ull : ~0ull;
                    remv |= R[k] & msk;
                    cur  |= rwv[k] & msk;
                }
            }
            kept_total += 64 - (int)__popcll(cur);
            if (c + 1 < NCHUNK && kept_total >= KEEP_POST) {
                if (lw > c) remv = ~0ull;     // force-suppress unprocessed rows
                if (tid == 0) ls_stop = 1;
            }
        }
        __syncthreads();
        if (ls_stop) break;
    }

    if (tid < MW) {
        u64 kw = ~remv;
        if (tid == MW - 1) kw &= (1ull << (KEEP_PRE - 64 * (MW - 1))) - 1ull;
        keepw[tid] = kw;
    }
    __syncthreads();
    if (tid == 0) {
        u32 cnt = 0;
        for (int w = 0; w < MW; w++) { wpre[w] = cnt; cnt += (u32)__popcll(keepw[w]); }
        wpre[MW] = cnt;
    }
    __syncthreads();
    const int total = (int)wpre[MW];
    float* outb = out + (size_t)b * KEEP_POST * 5;
    for (int i = tid; i < KEEP_PRE; i += 256) {
        int w = i >> 6;
        u64 kw = keepw[w];
        if ((kw >> (i & 63)) & 1ull) {
            int rank = (int)wpre[w] + __popcll(kw & ((1ull << (i & 63)) - 1ull));
            if (rank < KEEP_POST) {
                float4 bx = selbox[(size_t)b * KEEP_PRE + i];
                float sc = selscore[(size_t)b * KEEP_PRE + i];
                outb[rank * 5 + 0] = bx.x;
                outb[rank * 5 + 1] = bx.y;
                outb[rank * 5 + 2] = bx.z;
                outb[rank * 5 + 3] = bx.w;
                outb[rank * 5 + 4] = sc;
            }
        }
    }
    for (int r = tid; r < KEEP_POST; r += 256) {
        if (r >= total) {
            outb[r * 5 + 0] = 0.0f;
            outb[r * 5 + 1] = 0.0f;
            outb[r * 5 + 2] = 0.0f;
            outb[r * 5 + 3] = 0.0f;
            outb[r * 5 + 4] = 0.0f;
        }
    }
}

extern "C" void kernel_launch(void* const* d_in, const int* in_sizes, int n_in,
                              void* d_out, int out_size, void* d_ws, size_t ws_size,
                              hipStream_t stream) {
    const float* logits  = (const float*)d_in[0];   // [32,90000,1]
    const float* deltas  = (const float*)d_in[1];   // [32,90000,4]
    const float* anchors = (const float*)d_in[2];   // [90000,4]
    const int* p_img_h   = (const int*)d_in[3];
    const int* p_img_w   = (const int*)d_in[4];

    char* ws = (char*)d_ws;
    u32* hist     = (u32*)(ws);
    u32* cnt      = (u32*)(ws + CNT_OFF);
    u32* Bthr     = (u32*)(ws + BTHR_OFF);
    u64* cand     = (u64*)(ws + CAND_OFF);
    float4* selbox = (float4*)(ws + BOX_OFF);
    float* selscore = (float*)(ws + SCORE_OFF);
    u64* mask     = (u64*)(ws + MASK_OFF);

    // zero histogram + per-image candidate counters (ws is poisoned 0xAA each call)
    hipMemsetAsync(ws, 0, CNT_OFF + CNT_BYTES, stream);

    hist_kernel<<<dim3(16, BS), 256, 0, stream>>>(logits, hist);
    thresh_kernel<<<BS, 256, 0, stream>>>(hist, Bthr);
    compact_kernel<<<dim3((NANCH + 255) / 256, BS), 256, 0, stream>>>(logits, Bthr, cnt, cand);
    select_kernel<<<BS, 1024, 0, stream>>>(deltas, anchors, cnt, cand, selbox, selscore,
                                           p_img_h, p_img_w);
    iou_kernel<<<dim3(64, BS), 256, 0, stream>>>(selbox, mask);
    nms_out_kernel<<<BS, 256, 0, stream>>>(mask, selbox, selscore, (float*)d_out);
}

// Round 8
// 187.011 us; speedup vs baseline: 1.1661x; 1.1661x over previous
//
#include <hip/hip_runtime.h>
#include <stdint.h>

// Mimic numpy (no FMA contraction) for all math feeding discrete decisions.
#pragma clang fp contract(off)

#define BS 32
#define NANCH 90000
#define KEEP_PRE 1000
#define KEEP_POST 300
#define NMS_THR 0.7f
#define NBINS 4096      // top-12-bit histogram of monotone float bits
#define CAND_MAX 4096
#define MW 16           // u64 mask words per NMS row (16*64 = 1024 >= 1000)
#define CNT_STRIDE 32   // u32s between per-image counters (128 B = 1 cacheline)
#define NSLICE 8        // select_kernel: i-slices per image (CU spreading)

typedef unsigned long long u64;
typedef unsigned int u32;

// ---- workspace layout (bytes) ----
#define HIST_BYTES ((size_t)BS * NBINS * 4)          // 524288, zeroed each call
#define CNT_OFF    (HIST_BYTES)                      // u32[BS*CNT_STRIDE], zeroed
#define CNT_BYTES  ((size_t)BS * CNT_STRIDE * 4)     // 4096
#define BTHR_OFF   (CNT_OFF + CNT_BYTES)             // u32[BS]
#define CAND_OFF   (BTHR_OFF + 128)                  // u64[BS][CAND_MAX]
#define BOX_OFF    (CAND_OFF + (size_t)BS * CAND_MAX * 8)   // float4[BS][KEEP_PRE]
#define SCORE_OFF  (BOX_OFF + (size_t)BS * KEEP_PRE * 16)   // float[BS][KEEP_PRE]
#define MASK_OFF   (SCORE_OFF + (size_t)BS * KEEP_PRE * 4)  // u64[BS][KEEP_PRE][MW]
// total ~6.03 MB

__device__ __forceinline__ u32 fmono(float f) {
    u32 u = __float_as_uint(f);
    return (u & 0x80000000u) ? ~u : (u | 0x80000000u);  // order-preserving bits
}

// ---- Kernel A: per-image 4096-bin histogram of top-12 monotone bits ----
__global__ __launch_bounds__(256) void hist_kernel(const float* __restrict__ logits,
                                                   u32* __restrict__ hist) {
    __shared__ u32 lh[NBINS];
    const int b = blockIdx.y;
    for (int i = threadIdx.x; i < NBINS; i += 256) lh[i] = 0;
    __syncthreads();
    const float* src = logits + (size_t)b * NANCH;
    const int stride = 256 * gridDim.x;
    for (int i = blockIdx.x * 256 + threadIdx.x; i < NANCH; i += stride) {
        u32 m = fmono(src[i]);
        atomicAdd(&lh[m >> 20], 1u);
    }
    __syncthreads();
    u32* gh = hist + (size_t)b * NBINS;
    for (int i = threadIdx.x; i < NBINS; i += 256)
        if (lh[i]) atomicAdd(&gh[i], lh[i]);
}

// ---- Kernel B: find threshold bin B s.t. count(bin >= B) >= KEEP_PRE ----
__global__ __launch_bounds__(256) void thresh_kernel(const u32* __restrict__ hist,
                                                     u32* __restrict__ Bthr) {
    __shared__ u32 part[256];
    const int b = blockIdx.x;
    const u32* h = hist + (size_t)b * NBINS;
    u32 s = 0;
    for (int k = 0; k < 16; k++) s += h[threadIdx.x * 16 + k];
    part[threadIdx.x] = s;
    __syncthreads();
    if (threadIdx.x == 0) {
        u32 cum = 0;
        int c = 255;
        for (; c >= 0; c--) {
            if (cum + part[c] >= KEEP_PRE) break;
            cum += part[c];
        }
        if (c < 0) c = 0;
        int bin = c * 16 + 15;
        for (; bin >= c * 16; bin--) {
            if (cum + h[bin] >= KEEP_PRE) break;
            cum += h[bin];
        }
        if (bin < c * 16) bin = c * 16;
        Bthr[b] = (u32)bin;
    }
}

// ---- Kernel C: compact candidates (key = monotone<<32 | ~idx) ----
__global__ __launch_bounds__(256) void compact_kernel(const float* __restrict__ logits,
                                                      const u32* __restrict__ Bthr,
                                                      u32* __restrict__ cnt,
                                                      u64* __restrict__ cand) {
    const int b = blockIdx.y;
    const int i = blockIdx.x * 256 + threadIdx.x;
    __shared__ u32 blk_cnt;
    __shared__ u32 blk_base;
    if (threadIdx.x == 0) blk_cnt = 0;
    __syncthreads();
    bool is_cand = false;
    u32 m = 0;
    if (i < NANCH) {
        m = fmono(logits[(size_t)b * NANCH + i]);
        is_cand = (m >> 20) >= Bthr[b];
    }
    u64 ballot = __ballot(is_cand);
    const u32 lane = threadIdx.x & 63;
    u32 wbase = 0;
    u32 old = 0;
    if (ballot) {
        if (lane == 0) old = atomicAdd(&blk_cnt, (u32)__popcll(ballot));
        wbase = __shfl(old, 0);
    }
    __syncthreads();
    if (threadIdx.x == 0 && blk_cnt)
        blk_base = atomicAdd(&cnt[b * CNT_STRIDE], blk_cnt);
    __syncthreads();
    if (is_cand) {
        u32 prefix = (u32)__popcll(ballot & ((1ull << lane) - 1ull));
        u32 pos = blk_base + wbase + prefix;
        if (pos < CAND_MAX)
            cand[(size_t)b * CAND_MAX + pos] = ((u64)m << 32) | (u32)(~(u32)i);
    }
}

// ---- Kernel D: rank-select top 1000, sliced across NSLICE CUs per image ----
// rank(key) = #(strictly greater keys); keys unique -> permutation. Each block
// stages all n keys into ITS OWN CU's LDS (~8 KB) and ranks only its i-slice
// (~n/8 items, 2-3 active waves), so per-CU LDS issue is ~n reads/wave with
// 16 independent ds_read_b64 outstanding (issue-bound, latency hidden).
// Slice writes to selbox[rank] are disjoint (rank permutation).
__global__ __launch_bounds__(256) void select_kernel(const float* __restrict__ deltas,
                                                     const float* __restrict__ anchors,
                                                     const u32* __restrict__ cnt,
                                                     const u64* __restrict__ cand,
                                                     float4* __restrict__ selbox,
                                                     float* __restrict__ selscore,
                                                     const int* __restrict__ p_img_h,
                                                     const int* __restrict__ p_img_w) {
    __shared__ u64 keys[CAND_MAX];
    const int b = blockIdx.y;
    const int slice = blockIdx.x;                    // 0..NSLICE-1
    const int n = (int)min(cnt[b * CNT_STRIDE], (u32)CAND_MAX);
    const u64* src = cand + (size_t)b * CAND_MAX;
    for (int i = threadIdx.x; i < n; i += 256)
        keys[i] = src[i];
    __syncthreads();
    const int per = (n + NSLICE - 1) / NSLICE;
    const int i0 = slice * per;
    const int i1 = min(i0 + per, n);
    const float W = (float)(*p_img_w);
    const float H = (float)(*p_img_h);
    const float4* d4 = (const float4*)deltas;
    const float4* a4 = (const float4*)anchors;
    for (int i = i0 + threadIdx.x; i < i1; i += 256) {
        const u64 me = keys[i];
        int rank = 0;
        int j = 0;
        for (; j + 16 <= n; j += 16) {
            int r0 = 0;
#pragma unroll
            for (int k = 0; k < 16; k++) r0 += (keys[j + k] > me);
            rank += r0;
        }
        for (; j < n; j++) rank += (keys[j] > me);
        if (rank < KEEP_PRE) {
            u32 idx = ~(u32)me;
            u32 m = (u32)(me >> 32);
            u32 ub = (m & 0x80000000u) ? (m ^ 0x80000000u) : ~m;
            float logit = __uint_as_float(ub);
            float score = 1.0f / (1.0f + expf(-logit));
            float4 d = d4[(size_t)b * NANCH + idx];
            float4 a = a4[idx];
            float aw = a.z - a.x, ah = a.w - a.y;
            float acx = a.x + 0.5f * aw, acy = a.y + 0.5f * ah;
            float cx = d.x * aw + acx, cy = d.y * ah + acy;
            float w = expf(d.z) * aw, h = expf(d.w) * ah;
            float x1 = cx - 0.5f * w, y1 = cy - 0.5f * h;
            float x2 = cx + 0.5f * w, y2 = cy + 0.5f * h;
            x1 = fminf(fmaxf(x1, 0.0f), W); y1 = fminf(fmaxf(y1, 0.0f), H);
            x2 = fminf(fmaxf(x2, 0.0f), W); y2 = fminf(fmaxf(y2, 0.0f), H);
            selbox[(size_t)b * KEEP_PRE + rank] = make_float4(x1, y1, x2, y2);
            selscore[(size_t)b * KEEP_PRE + rank] = score;
        }
    }
}

// ---- Kernel E: IoU>thr suppression bitmask, mask[b][i][w] covers cols 64w..64w+63 ----
__global__ __launch_bounds__(256) void iou_kernel(const float4* __restrict__ selbox,
                                                  u64* __restrict__ mask) {
    const int b = blockIdx.y;
    const int w = blockIdx.x & 15;
    const int chunk = blockIdx.x >> 4;
    const int i = chunk * 256 + threadIdx.x;
    __shared__ float4 cb[64];
    __shared__ float ca[64];
    if (threadIdx.x < 64) {
        int j = w * 64 + threadIdx.x;
        float4 bx = (j < KEEP_PRE) ? selbox[(size_t)b * KEEP_PRE + j]
                                   : make_float4(0, 0, 0, 0);
        cb[threadIdx.x] = bx;
        ca[threadIdx.x] = (bx.z - bx.x) * (bx.w - bx.y);
    }
    __syncthreads();
    if (i >= KEEP_PRE) return;
    float4 bi = selbox[(size_t)b * KEEP_PRE + i];
    float ai = (bi.z - bi.x) * (bi.w - bi.y);
    u64 bits = 0;
    const int jbase = w * 64;
    for (int jj = 0; jj < 64; jj++) {
        int j = jbase + jj;
        if (j > i && j < KEEP_PRE) {
            float4 bj = cb[jj];
            float ltx = fmaxf(bi.x, bj.x), lty = fmaxf(bi.y, bj.y);
            float rbx = fminf(bi.z, bj.z), rby = fminf(bi.w, bj.w);
            float wx = fmaxf(rbx - ltx, 0.0f), wy = fmaxf(rby - lty, 0.0f);
            float inter = wx * wy;
            float denom = ai + ca[jj] - inter + 1e-12f;
            if (inter / denom > NMS_THR) bits |= (1ull << jj);
        }
    }
    mask[((size_t)b * KEEP_PRE + i) * MW + w] = bits;
}

// ---- Kernel F: sequential greedy NMS, word-aligned branchless scan ----
#define CH_ROWS 64
#define CH_WORDS (CH_ROWS * MW)          // 1024 u64 = 8 KB
#define NCHUNK ((KEEP_PRE + CH_ROWS - 1) / CH_ROWS)   // 16 (last chunk 40 rows)

__global__ __launch_bounds__(256) void nms_out_kernel(const u64* __restrict__ mask,
                                                      const float4* __restrict__ selbox,
                                                      const float* __restrict__ selscore,
                                                      float* __restrict__ out) {
    const int b = blockIdx.x;
    __shared__ u64 lbuf[2][CH_WORDS];
    __shared__ u64 keepw[MW];
    __shared__ u32 wpre[MW + 1];
    __shared__ int ls_stop;
    const int tid = threadIdx.x;
    const u64* mrow = mask + (size_t)b * KEEP_PRE * MW;

    auto load_chunk = [&](int c) {
        int idx = tid - 128;
        if (idx < 0) return;
        const int words = (c == NCHUNK - 1)
                            ? (KEEP_PRE - (NCHUNK - 1) * CH_ROWS) * MW   // 640
                            : CH_WORDS;                                  // 1024
        const u64* gsrc = mrow + (size_t)c * CH_WORDS;
        u64* dst = lbuf[c & 1];
#pragma unroll
        for (int k = 0; k < 4; k++) {
            int off = k * 256 + idx * 2;
            ulonglong2 v;
            if (off < words) v = *(const ulonglong2*)(gsrc + off);
            else { v.x = 0ull; v.y = 0ull; }
            *(ulonglong2*)(dst + off) = v;
        }
    };

    if (tid == 0) ls_stop = 0;
    load_chunk(0);
    __syncthreads();

    u64 remv = 0;
    int kept_total = 0;
    const int lw = tid & 15;
    for (int c = 0; c < NCHUNK; c++) {
        if (c + 1 < NCHUNK) load_chunk(c + 1);
        if (tid < 64) {
            const u64* lb = lbuf[c & 1];
            u64 cur = __shfl(remv, c);   // word c of accumulated suppression
#pragma unroll
            for (int blk = 0; blk < 8; blk++) {
                u64 R[8], rwv[8];
#pragma unroll
                for (int k = 0; k < 8; k++)
                    R[k] = lb[(size_t)(blk * 8 + k) * MW + lw];       // lane word
#pragma unroll
                for (int k = 0; k < 8; k++)
                    rwv[k] = lb[(size_t)(blk * 8 + k) * MW + c];      // broadcast word c
#pragma unroll
                for (int k = 0; k < 8; k++) {
                    const int p = blk * 8 + k;                        // compile-time
                    u64 msk = ((cur >> p) & 1ull) ? 0ull : ~0ull;
                    remv |= R[k] & msk;
                    cur  |= rwv[k] & msk;
                }
            }
            kept_total += 64 - (int)__popcll(cur);
            if (c + 1 < NCHUNK && kept_total >= KEEP_POST) {
                if (lw > c) remv = ~0ull;     // force-suppress unprocessed rows
                if (tid == 0) ls_stop = 1;
            }
        }
        __syncthreads();
        if (ls_stop) break;
    }

    if (tid < MW) {
        u64 kw = ~remv;
        if (tid == MW - 1) kw &= (1ull << (KEEP_PRE - 64 * (MW - 1))) - 1ull;
        keepw[tid] = kw;
    }
    __syncthreads();
    if (tid == 0) {
        u32 cnt = 0;
        for (int w = 0; w < MW; w++) { wpre[w] = cnt; cnt += (u32)__popcll(keepw[w]); }
        wpre[MW] = cnt;
    }
    __syncthreads();
    const int total = (int)wpre[MW];
    float* outb = out + (size_t)b * KEEP_POST * 5;
    for (int i = tid; i < KEEP_PRE; i += 256) {
        int w = i >> 6;
        u64 kw = keepw[w];
        if ((kw >> (i & 63)) & 1ull) {
            int rank = (int)wpre[w] + __popcll(kw & ((1ull << (i & 63)) - 1ull));
            if (rank < KEEP_POST) {
                float4 bx = selbox[(size_t)b * KEEP_PRE + i];
                float sc = selscore[(size_t)b * KEEP_PRE + i];
                outb[rank * 5 + 0] = bx.x;
                outb[rank * 5 + 1] = bx.y;
                outb[rank * 5 + 2] = bx.z;
                outb[rank * 5 + 3] = bx.w;
                outb[rank * 5 + 4] = sc;
            }
        }
    }
    for (int r = tid; r < KEEP_POST; r += 256) {
        if (r >= total) {
            outb[r * 5 + 0] = 0.0f;
            outb[r * 5 + 1] = 0.0f;
            outb[r * 5 + 2] = 0.0f;
            outb[r * 5 + 3] = 0.0f;
            outb[r * 5 + 4] = 0.0f;
        }
    }
}

extern "C" void kernel_launch(void* const* d_in, const int* in_sizes, int n_in,
                              void* d_out, int out_size, void* d_ws, size_t ws_size,
                              hipStream_t stream) {
    const float* logits  = (const float*)d_in[0];   // [32,90000,1]
    const float* deltas  = (const float*)d_in[1];   // [32,90000,4]
    const float* anchors = (const float*)d_in[2];   // [90000,4]
    const int* p_img_h   = (const int*)d_in[3];
    const int* p_img_w   = (const int*)d_in[4];

    char* ws = (char*)d_ws;
    u32* hist     = (u32*)(ws);
    u32* cnt      = (u32*)(ws + CNT_OFF);
    u32* Bthr     = (u32*)(ws + BTHR_OFF);
    u64* cand     = (u64*)(ws + CAND_OFF);
    float4* selbox = (float4*)(ws + BOX_OFF);
    float* selscore = (float*)(ws + SCORE_OFF);
    u64* mask     = (u64*)(ws + MASK_OFF);

    // zero histogram + per-image candidate counters (ws is poisoned 0xAA each call)
    hipMemsetAsync(ws, 0, CNT_OFF + CNT_BYTES, stream);

    hist_kernel<<<dim3(16, BS), 256, 0, stream>>>(logits, hist);
    thresh_kernel<<<BS, 256, 0, stream>>>(hist, Bthr);
    compact_kernel<<<dim3((NANCH + 255) / 256, BS), 256, 0, stream>>>(logits, Bthr, cnt, cand);
    select_kernel<<<dim3(NSLICE, BS), 256, 0, stream>>>(deltas, anchors, cnt, cand,
                                                        selbox, selscore, p_img_h, p_img_w);
    iou_kernel<<<dim3(64, BS), 256, 0, stream>>>(selbox, mask);
    nms_out_kernel<<<BS, 256, 0, stream>>>(mask, selbox, selscore, (float*)d_out);
}